// Round 1
// baseline (112.710 us; speedup 1.0000x reference)
//
#include <hip/hip_runtime.h>
#include <hip/hip_bf16.h>
#include <math.h>

#define N 8192
#define D 64
#define INVT 20.0f
#define EPS 1e-6f
// sqrt(20/ln2): gram(Z) = 20*log2(e)*cos, so exp2(gram) = e^{20 cos}
#define ZSCALE 5.3715835f

typedef __attribute__((ext_vector_type(8))) short bf16x8;
typedef __attribute__((ext_vector_type(4))) float f32x4;

#if __has_builtin(__builtin_amdgcn_exp2f)
#define EXP2F(x) __builtin_amdgcn_exp2f(x)
#else
#define EXP2F(x) exp2f(x)
#endif

// Z layout (fragment order): G-row R, element l stored at bf16 index
//   ( (R>>4)*128 + (l>>5)*64 + ((l>>3)&3)*16 + (R&15) )*8 + (l&7)
// so the MFMA fragment load for 16-row group g, K-chunk kc is the fully
// contiguous 1 KB wave load  Zf[g*128 + kc*64 + lane].
//
// HISTORY (keep):
//  - R9/R12: (256,5) cap=102 regs -> spills BOTH times (WRITE 83-85MB, 2-3x
//    slower). Live set needs ~110-120 unified regs. 4 waves/SIMD [(256,4),
//    cap 128] is the occupancy ceiling. Do not retry (256,5).
//  - R10: __threadfence in all blocks -> L2 thrash, 5x slower.
//  - R11 (=R8, best 93.1us): 1 tile/block, af+bv resident, (256,4).
//  - R13 (91.8us): 2 ranks/block, tile1 frags prefetched during tile0 epilogue.
//  - R14 (this): strip-mining. 1024 blocks x ~8 consecutive ranks. A-frags
//    register-resident per row segment; row sums accumulate in regs
//    (rsum[4][4]) and flush via LDS transpose only on row change (~1.3K
//    flushes vs 16.5K). Col sums flush per tile via shfl + direct per-lane
//    atomic (no cmerged LDS, no barrier). Zero per-tile __syncthreads ->
//    waves drift, trans/VALU/MFMA pipes overlap; L2 fragment traffic ~halved.

__device__ __forceinline__ void unrank(int t, int& bi, int& bj) {
    int b = (int)((257.0f - sqrtf(66049.0f - 8.0f * (float)t)) * 0.5f);
    while (b * (257 - b) / 2 > t) --b;
    while ((b + 1) * (256 - b) / 2 <= t) ++b;
    bi = b;
    bj = b + (t - b * (257 - b) / 2);
}

// ---------------- Kernel 1: normalize -> scaled bf16 Z (fragment order),
//                  zero part[] / lacc / cnt ----------------
__global__ __launch_bounds__(256) void prep_kernel(
    const float* __restrict__ A, const float* __restrict__ P,
    __hip_bfloat16* __restrict__ Zn, float* __restrict__ diag20,
    float* __restrict__ part, float* __restrict__ lacc, unsigned* __restrict__ cnt) {
    if (blockIdx.x < 64) part[blockIdx.x * 256 + threadIdx.x] = 0.0f;
    else if (blockIdx.x == 64 && threadIdx.x == 0) { *lacc = 0.0f; *cnt = 0u; }

    const int lane = threadIdx.x & 63;   // element index l
    const int w    = threadIdx.x >> 6;
    const int r    = blockIdx.x * 4 + w; // A/P row
    const int u    = lane >> 3, sub = lane & 7;
    const int upos = (u >> 2) * 64 + (u & 3) * 16;   // kc*64 + q*16

    float a = A[r * D + lane];
    float p = P[r * D + lane];
    float sa = a * a, sp = p * p, dp = a * p;
    #pragma unroll
    for (int off = 1; off < 64; off <<= 1) {
        sa += __shfl_xor(sa, off, 64);
        sp += __shfl_xor(sp, off, 64);
        dp += __shfl_xor(dp, off, 64);
    }
    float na  = sqrtf(sa);
    float npn = sqrtf(sp);
    {   // A-row R = r
        int g = r >> 4, l2 = r & 15;
        Zn[(g * 128 + upos + l2) * 8 + sub] = __float2bfloat16(a * (ZSCALE / na));
    }
    {   // P-row R = N + r
        int R = N + r; int g = R >> 4, l2 = R & 15;
        Zn[(g * 128 + upos + l2) * 8 + sub] = __float2bfloat16(p * (ZSCALE / npn));
    }
    if (lane == 0)
        diag20[r] = (dp / fmaxf(na * npn, EPS)) * INVT;
}

// ---------------- Kernel 2: strip-mined triangular tiles ----------------
__global__ __launch_bounds__(256, 4) void tiles_kernel(
    const __hip_bfloat16* __restrict__ Zn, float* __restrict__ part) {
    __shared__ float rs[4][16][68];     // wave-local transpose for row flush
    __shared__ float merged[2][128];    // row merge over wc (flush only)

    const int tid = threadIdx.x;
    const int lane = tid & 63, w = tid >> 6;
    const int wr = w >> 1, wc = w & 1;
    const int ln = lane & 15, q = lane >> 4;
    const bf16x8* Zf = (const bf16x8*)Zn;
    const f32x4 zero = {0.0f, 0.0f, 0.0f, 0.0f};

    // 8256 ranks over 1024 blocks: first 64 blocks take 9, rest take 8.
    const int b = (int)blockIdx.x;
    const int ntiles = (b < 64) ? 9 : 8;
    int bi, bj;
    unrank(b * 8 + ((b < 64) ? b : 64), bi, bj);

    // A fragments, register-resident for the current row segment
    bf16x8 af[4][2];
    #pragma unroll
    for (int ii = 0; ii < 4; ++ii) {
        int ga = bi * 8 + wr * 4 + ii;
        af[ii][0] = Zf[ga * 128 + lane];
        af[ii][1] = Zf[ga * 128 + 64 + lane];
    }

    float rsum[4][4] = {{0.0f}};   // [ii][r] row-sum accumulators

    for (int t = 0; t < ntiles; ++t) {
        // ---- load B fragments for this tile ----
        bf16x8 bv[4][2];
        #pragma unroll
        for (int ii = 0; ii < 4; ++ii) {
            int gb = bj * 8 + wc * 4 + ii;
            bv[ii][0] = Zf[gb * 128 + lane];
            bv[ii][1] = Zf[gb * 128 + 64 + lane];
        }

        const bool dwave = (bi == bj) && (wr == wc);
        float csum[4] = {0.0f, 0.0f, 0.0f, 0.0f};
        #pragma unroll
        for (int ii = 0; ii < 4; ++ii) {
            f32x4 acc[4];
            #pragma unroll
            for (int jj = 0; jj < 4; ++jj)
                acc[jj] = __builtin_amdgcn_mfma_f32_16x16x32_bf16(
                    af[ii][0], bv[jj][0], zero, 0, 0, 0);
            #pragma unroll
            for (int jj = 0; jj < 4; ++jj)
                acc[jj] = __builtin_amdgcn_mfma_f32_16x16x32_bf16(
                    af[ii][1], bv[jj][1], acc[jj], 0, 0, 0);

            #pragma unroll
            for (int jj = 0; jj < 4; ++jj) {
                f32x4 e;
                #pragma unroll
                for (int r = 0; r < 4; ++r) e[r] = EXP2F(acc[jj][r]);
                if (dwave && (ii == jj)) {
                    #pragma unroll
                    for (int r = 0; r < 4; ++r)
                        if (ln == q * 4 + r) e[r] = 0.0f;
                }
                #pragma unroll
                for (int r = 0; r < 4; ++r) rsum[ii][r] += e[r];
                csum[jj] += (e[0] + e[1]) + (e[2] + e[3]);
            }
        }

        // ---- per-tile column flush (skip diag: rows cover it) ----
        if (bi != bj) {
            float cs0 = csum[0], cs1 = csum[1], cs2 = csum[2], cs3 = csum[3];
            cs0 += __shfl_xor(cs0, 16, 64); cs0 += __shfl_xor(cs0, 32, 64);
            cs1 += __shfl_xor(cs1, 16, 64); cs1 += __shfl_xor(cs1, 32, 64);
            cs2 += __shfl_xor(cs2, 16, 64); cs2 += __shfl_xor(cs2, 32, 64);
            cs3 += __shfl_xor(cs3, 16, 64); cs3 += __shfl_xor(cs3, 32, 64);
            float cval = (q == 0) ? cs0 : (q == 1) ? cs1 : (q == 2) ? cs2 : cs3;
            // col = bj*128 + wc*64 + (q*16+ln) = bj*128 + wc*64 + lane
            atomicAdd(part + bj * 128 + wc * 64 + lane, cval);
        }

        // ---- advance; flush rows only when the row segment ends ----
        if (t + 1 < ntiles) {
            if (bj == 127) {
                // row flush for bi
                #pragma unroll
                for (int ii = 0; ii < 4; ++ii)
                    *(f32x4*)&rs[w][ln][ii * 16 + q * 4] = *(const f32x4*)&rsum[ii][0];
                float rowsum = 0.0f;
                #pragma unroll
                for (int l = 0; l < 16; ++l) rowsum += rs[w][l][lane];
                merged[wc][wr * 64 + lane] = rowsum;
                __syncthreads();
                if (tid < 128)
                    atomicAdd(part + bi * 128 + tid, merged[0][tid] + merged[1][tid]);
                __syncthreads();   // protect merged before next flush rewrites it
                #pragma unroll
                for (int ii = 0; ii < 4; ++ii) {
                    #pragma unroll
                    for (int r = 0; r < 4; ++r) rsum[ii][r] = 0.0f;
                }
                ++bi; bj = bi;
                #pragma unroll
                for (int ii = 0; ii < 4; ++ii) {
                    int ga = bi * 8 + wr * 4 + ii;
                    af[ii][0] = Zf[ga * 128 + lane];
                    af[ii][1] = Zf[ga * 128 + 64 + lane];
                }
            } else {
                ++bj;
            }
        }
    }

    // ---- final row flush ----
    #pragma unroll
    for (int ii = 0; ii < 4; ++ii)
        *(f32x4*)&rs[w][ln][ii * 16 + q * 4] = *(const f32x4*)&rsum[ii][0];
    float rowsum = 0.0f;
    #pragma unroll
    for (int l = 0; l < 16; ++l) rowsum += rs[w][l][lane];
    merged[wc][wr * 64 + lane] = rowsum;
    __syncthreads();
    if (tid < 128)
        atomicAdd(part + bi * 128 + tid, merged[0][tid] + merged[1][tid]);
}

// ---------------- Kernel 3: per-row loss + reduce + last-block finalize ------
__global__ __launch_bounds__(256) void loss_kernel(
    const float* __restrict__ part, const float* __restrict__ diag20,
    float* __restrict__ lacc, unsigned* __restrict__ cnt, float* __restrict__ out) {
    int i = blockIdx.x * 256 + threadIdx.x;
    float v = logf(part[i] + part[N + i]) - diag20[i];
    #pragma unroll
    for (int off = 32; off > 0; off >>= 1) v += __shfl_down(v, off, 64);
    __shared__ float wsm[4];
    int lane = threadIdx.x & 63, wv = threadIdx.x >> 6;
    if (lane == 0) wsm[wv] = v;
    __syncthreads();
    if (threadIdx.x == 0) {
        atomicAdd(lacc, wsm[0] + wsm[1] + wsm[2] + wsm[3]);
        __threadfence();
        unsigned old = atomicAdd(cnt, 1u);
        if (old == (N / 256 - 1)) {
            float tot = atomicAdd(lacc, 0.0f);
            out[0] = tot * (1.0f / (float)N);
        }
    }
}

// ---------------- launch ----------------
extern "C" void kernel_launch(void* const* d_in, const int* in_sizes, int n_in,
                              void* d_out, int out_size, void* d_ws, size_t ws_size,
                              hipStream_t stream) {
    const float* A = (const float*)d_in[0];
    const float* P = (const float*)d_in[1];

    __hip_bfloat16* Zn = (__hip_bfloat16*)d_ws;                 // 2N*64 bf16 = 2 MiB
    float* diag20 = (float*)((char*)d_ws + 2u * N * D * sizeof(__hip_bfloat16));
    float* part   = diag20 + N;          // 2N floats, atomic-accumulated
    float* lacc   = part + 2 * N;
    unsigned* cnt = (unsigned*)(lacc + 1);

    prep_kernel<<<N / 4, 256, 0, stream>>>(A, P, Zn, diag20, part, lacc, cnt);

    tiles_kernel<<<1024, 256, 0, stream>>>(Zn, part);

    loss_kernel<<<N / 256, 256, 0, stream>>>(part, diag20, lacc, cnt, (float*)d_out);
}